// Round 1
// baseline (247.645 us; speedup 1.0000x reference)
//
#include <hip/hip_runtime.h>

#define NCLS   4096
#define BATCHN 65536
#define TOPK   4096
#define ALPHA  2.0f

// ---------------------------------------------------------------------------
// Kernel 0: detect whether link_table arrived as int32 (words all 0/1) or as
// 1-byte bool (packed bytes -> many words > 1). Deterministic for the dataset.
// ---------------------------------------------------------------------------
__global__ void detect_int32_kernel(const unsigned int* __restrict__ lt,
                                    int* __restrict__ flag) {
    int tid = threadIdx.x;  // 64 threads
    unsigned int bad = 0;
    for (int i = tid; i < 1024; i += 64) bad |= (lt[i] > 1u) ? 1u : 0u;
    unsigned long long mask = __ballot(bad != 0);
    if (tid == 0) flag[0] = (mask == 0ULL) ? 1 : 0;  // 1 => int32 storage
}

__device__ inline void amax_comb(float& m, int& mi, float om, int omi) {
    // max value; ties -> smallest index (jnp.argmax takes first occurrence)
    if (om > m || (om == m && omi < mi)) { m = om; mi = omi; }
}

// ---------------------------------------------------------------------------
// Kernel 1: one block per row. Single pass over the row (held in registers).
// ---------------------------------------------------------------------------
__global__ __launch_bounds__(256) void row_loss_kernel(
    const float* __restrict__ yp, const int* __restrict__ yt,
    const unsigned char* __restrict__ lt, const int* __restrict__ flag,
    float* __restrict__ losses) {
    const int b   = blockIdx.x;
    const int tid = threadIdx.x;
    const float4* row = reinterpret_cast<const float4*>(yp + (size_t)b * NCLS);

    float4 v0 = row[0 * 256 + tid];
    float4 v1 = row[1 * 256 + tid];
    float4 v2 = row[2 * 256 + tid];
    float4 v3 = row[3 * 256 + tid];

    // local max/argmax; columns for chunk j are j*1024 + tid*4 + k (ascending)
    float m = -3.4e38f; int mi = 0;
    {
        const int c0 = tid * 4;
        if (v0.x > m) { m = v0.x; mi = c0 + 0; }
        if (v0.y > m) { m = v0.y; mi = c0 + 1; }
        if (v0.z > m) { m = v0.z; mi = c0 + 2; }
        if (v0.w > m) { m = v0.w; mi = c0 + 3; }
        const int c1 = 1024 + tid * 4;
        if (v1.x > m) { m = v1.x; mi = c1 + 0; }
        if (v1.y > m) { m = v1.y; mi = c1 + 1; }
        if (v1.z > m) { m = v1.z; mi = c1 + 2; }
        if (v1.w > m) { m = v1.w; mi = c1 + 3; }
        const int c2 = 2048 + tid * 4;
        if (v2.x > m) { m = v2.x; mi = c2 + 0; }
        if (v2.y > m) { m = v2.y; mi = c2 + 1; }
        if (v2.z > m) { m = v2.z; mi = c2 + 2; }
        if (v2.w > m) { m = v2.w; mi = c2 + 3; }
        const int c3 = 3072 + tid * 4;
        if (v3.x > m) { m = v3.x; mi = c3 + 0; }
        if (v3.y > m) { m = v3.y; mi = c3 + 1; }
        if (v3.z > m) { m = v3.z; mi = c3 + 2; }
        if (v3.w > m) { m = v3.w; mi = c3 + 3; }
    }

    // wave (64-lane) argmax reduce
    #pragma unroll
    for (int off = 32; off > 0; off >>= 1) {
        float om  = __shfl_down(m, off, 64);
        int   omi = __shfl_down(mi, off, 64);
        amax_comb(m, mi, om, omi);
    }

    __shared__ float wmax[4];
    __shared__ int   wmi[4];
    __shared__ float wsum[4];
    __shared__ float s_M;
    __shared__ int   s_pred;
    __shared__ float s_true;

    const int wid = tid >> 6, lane = tid & 63;
    if (lane == 0) { wmax[wid] = m; wmi[wid] = mi; }
    __syncthreads();
    if (tid == 0) {
        float M = wmax[0]; int P = wmi[0];
        amax_comb(M, P, wmax[1], wmi[1]);
        amax_comb(M, P, wmax[2], wmi[2]);
        amax_comb(M, P, wmax[3], wmi[3]);
        s_M = M; s_pred = P;
    }
    __syncthreads();
    const float M = s_M;

    float sum = 0.f;
    sum += __expf(v0.x - M); sum += __expf(v0.y - M);
    sum += __expf(v0.z - M); sum += __expf(v0.w - M);
    sum += __expf(v1.x - M); sum += __expf(v1.y - M);
    sum += __expf(v1.z - M); sum += __expf(v1.w - M);
    sum += __expf(v2.x - M); sum += __expf(v2.y - M);
    sum += __expf(v2.z - M); sum += __expf(v2.w - M);
    sum += __expf(v3.x - M); sum += __expf(v3.y - M);
    sum += __expf(v3.z - M); sum += __expf(v3.w - M);

    #pragma unroll
    for (int off = 32; off > 0; off >>= 1) sum += __shfl_down(sum, off, 64);

    const int gt = yt[b];
    // owner of column gt: chunk j = gt>>10, thread (gt>>2)&255, slot gt&3
    if (tid == ((gt >> 2) & 255)) {
        const int j = gt >> 10, k = gt & 3;
        float4 vv = (j == 0) ? v0 : (j == 1) ? v1 : (j == 2) ? v2 : v3;
        float t = (k == 0) ? vv.x : (k == 1) ? vv.y : (k == 2) ? vv.z : vv.w;
        s_true = t;
    }
    if (lane == 0) wsum[wid] = sum;
    __syncthreads();

    if (tid == 0) {
        float tot = wsum[0] + wsum[1] + wsum[2] + wsum[3];
        float ce  = logf(tot) + s_M - s_true;
        int pred  = s_pred;
        float factor = 1.0f;
        if (pred != gt) {
            size_t idx = (size_t)gt * NCLS + (size_t)pred;
            int linked = flag[0] ? ((const int*)lt)[idx] : (int)lt[idx];
            if (linked) factor = ALPHA;
        }
        losses[b] = factor * ce;
    }
}

// ---------------------------------------------------------------------------
// Kernel 2: exact mean of top-K via 3-level radix select on float bits
// (losses >= 0 so bit pattern order == float order). Single block.
// ---------------------------------------------------------------------------
__device__ void find_thresh_4096(unsigned int* hist, unsigned int* superb,
                                 int* s_t, unsigned int* s_above,
                                 unsigned int kneed, int tid) {
    if (tid < 64) {
        unsigned int s = 0;
        #pragma unroll 8
        for (int i = 0; i < 64; ++i) s += hist[tid * 64 + i];
        superb[tid] = s;
    }
    __syncthreads();
    if (tid == 0) {
        unsigned int cum = 0; int sb = 63;
        for (; sb > 0; --sb) {
            if (cum + superb[sb] >= kneed) break;
            cum += superb[sb];
        }
        const int lo = sb * 64;
        int t = lo + 63;
        for (; t > lo; --t) {
            if (cum + hist[t] >= kneed) break;
            cum += hist[t];
        }
        *s_t = t; *s_above = cum;
    }
    __syncthreads();
}

__global__ __launch_bounds__(1024) void topk_mean_kernel(
    const float* __restrict__ losses, float* __restrict__ out) {
    __shared__ unsigned int hist[4096];
    __shared__ unsigned int superb[64];
    __shared__ int          s_t;
    __shared__ unsigned int s_above;
    __shared__ unsigned int s_cntgt;
    __shared__ double       dsum[1024];

    const int tid = threadIdx.x;
    const int N = BATCHN, K = TOPK;
    unsigned int kneed = K;

    // ---- level 1: bits [31:20]
    for (int i = tid; i < 4096; i += 1024) hist[i] = 0;
    __syncthreads();
    for (int i = tid; i < N; i += 1024) {
        unsigned int key = __float_as_uint(losses[i]);
        atomicAdd(&hist[key >> 20], 1u);
    }
    __syncthreads();
    find_thresh_4096(hist, superb, &s_t, &s_above, kneed, tid);
    const unsigned int t1 = (unsigned int)s_t;
    kneed -= s_above;
    __syncthreads();

    // ---- level 2: bits [19:8] among candidates with key>>20 == t1
    for (int i = tid; i < 4096; i += 1024) hist[i] = 0;
    __syncthreads();
    for (int i = tid; i < N; i += 1024) {
        unsigned int key = __float_as_uint(losses[i]);
        if ((key >> 20) == t1) atomicAdd(&hist[(key >> 8) & 0xFFFu], 1u);
    }
    __syncthreads();
    find_thresh_4096(hist, superb, &s_t, &s_above, kneed, tid);
    const unsigned int t2 = (unsigned int)s_t;
    kneed -= s_above;
    __syncthreads();

    // ---- level 3: bits [7:0] among candidates with key>>8 == prefix
    const unsigned int pref = (t1 << 12) | t2;  // 24-bit prefix
    for (int i = tid; i < 256; i += 1024) hist[i] = 0;
    __syncthreads();
    for (int i = tid; i < N; i += 1024) {
        unsigned int key = __float_as_uint(losses[i]);
        if ((key >> 8) == pref) atomicAdd(&hist[key & 0xFFu], 1u);
    }
    __syncthreads();
    if (tid == 0) {
        unsigned int cum = 0; int t = 255;
        for (; t > 0; --t) {
            if (cum + hist[t] >= kneed) break;
            cum += hist[t];
        }
        s_t = t; s_above = cum;
    }
    __syncthreads();
    const unsigned int t3 = (unsigned int)s_t;
    const unsigned int T  = (pref << 8) | t3;   // full threshold bit pattern

    // ---- final: sum of strictly-greater + ties at T
    double local = 0.0; unsigned int cgt = 0;
    for (int i = tid; i < N; i += 1024) {
        unsigned int key = __float_as_uint(losses[i]);
        if (key > T) { local += (double)__uint_as_float(key); cgt++; }
    }
    dsum[tid] = local;
    if (tid == 0) s_cntgt = 0;
    __syncthreads();
    atomicAdd(&s_cntgt, cgt);
    __syncthreads();
    for (int s = 512; s > 0; s >>= 1) {
        if (tid < s) dsum[tid] += dsum[tid + s];
        __syncthreads();
    }
    if (tid == 0) {
        unsigned int ngt = s_cntgt;  // count strictly > T (< K by construction)
        double total = dsum[0] +
                       (double)(K - ngt) * (double)__uint_as_float(T);
        out[0] = (float)(total / (double)K);
    }
}

// ---------------------------------------------------------------------------
extern "C" void kernel_launch(void* const* d_in, const int* in_sizes, int n_in,
                              void* d_out, int out_size, void* d_ws, size_t ws_size,
                              hipStream_t stream) {
    const float* y_pred        = (const float*)d_in[0];
    const int* y_true          = (const int*)d_in[1];
    const unsigned char* lt    = (const unsigned char*)d_in[2];
    float* out                 = (float*)d_out;

    int*   flag   = (int*)d_ws;
    float* losses = (float*)((char*)d_ws + 1024);

    detect_int32_kernel<<<1, 64, 0, stream>>>((const unsigned int*)lt, flag);
    row_loss_kernel<<<BATCHN, 256, 0, stream>>>(y_pred, y_true, lt, flag, losses);
    topk_mean_kernel<<<1, 1024, 0, stream>>>(losses, out);
}